// Round 1
// baseline (805.935 us; speedup 1.0000x reference)
//
#include <hip/hip_runtime.h>

typedef __bf16 bfrag __attribute__((ext_vector_type(8)));
typedef float f32x4 __attribute__((ext_vector_type(4)));

__device__ __forceinline__ unsigned short f2bf(float f) {
    unsigned int u = __float_as_uint(f);
    unsigned int r = (u + 0x7fffu + ((u >> 16) & 1u)) >> 16;
    return (unsigned short)r;
}
__device__ __forceinline__ float bf2f(unsigned short h) {
    return __uint_as_float(((unsigned int)h) << 16);
}

// C = A[M,K] * B^T (BT=true: B is [N,K]) or A*B (BT=false: B is [K,N], transpose-staged).
// EPI: 0 = store bf16 (v*scale), 1 = sigmoid -> bf16, 2 = +bias[col] + residual bf16 -> f32
template<int BM, int BN, int EPI, bool BT>
__global__ __launch_bounds__(256) void gemm_k(
    const unsigned short* __restrict__ A, const unsigned short* __restrict__ B,
    unsigned short* __restrict__ Cb, float* __restrict__ Cf,
    const unsigned short* __restrict__ R, const float* __restrict__ bias,
    int M, int N, int K, float scale)
{
    constexpr int BK = 32;
    constexpr int LSTR = BK + 8;          // +8 bf16 pad keeps 16B alignment, breaks pow2 bank stride
    constexpr int WTM = BM / 32;          // 16x16 m-tiles per wave (2x2 wave grid)
    constexpr int WTN = BN / 32;
    __shared__ unsigned short sA[BM * LSTR];
    __shared__ unsigned short sB[BN * LSTR];

    const int tid  = threadIdx.x;
    const int wave = tid >> 6;
    const int lane = tid & 63;
    const int wm = wave >> 1;
    const int wn = wave & 1;
    const int bm0 = blockIdx.x * BM;
    const int bn0 = blockIdx.y * BN;
    const int mrow = lane & 15;
    const int kgrp = lane >> 4;

    f32x4 acc[WTM][WTN] = {};

    for (int k0 = 0; k0 < K; k0 += BK) {
        {   // stage A tile [BM x 32], 16B vector loads
            constexpr int PER = (BM * BK / 8) / 256;
            #pragma unroll
            for (int i = 0; i < PER; ++i) {
                int idx = tid + i * 256;
                int r = idx >> 2, c = idx & 3;
                uint4 d = *(const uint4*)(A + (size_t)(bm0 + r) * K + k0 + c * 8);
                *(uint4*)&sA[r * LSTR + c * 8] = d;
            }
        }
        if (BT) {  // B is [N,K]: same pattern as A
            constexpr int PER = (BN * BK / 8) / 256;
            #pragma unroll
            for (int i = 0; i < PER; ++i) {
                int idx = tid + i * 256;
                int r = idx >> 2, c = idx & 3;
                uint4 d = *(const uint4*)(B + (size_t)(bn0 + r) * K + k0 + c * 8);
                *(uint4*)&sB[r * LSTR + c * 8] = d;
            }
        } else {   // B is [K,N]: coalesced 16B reads, transposed scalar LDS stores
            constexpr int XPR = BN / 8;
            constexpr int PER = (BK * BN / 8) / 256;
            #pragma unroll
            for (int i = 0; i < PER; ++i) {
                int idx = tid + i * 256;
                int r = idx / XPR, c = idx % XPR;
                uint4 d = *(const uint4*)(B + (size_t)(k0 + r) * N + bn0 + c * 8);
                const unsigned short* u = (const unsigned short*)&d;
                #pragma unroll
                for (int j = 0; j < 8; ++j)
                    sB[(c * 8 + j) * LSTR + r] = u[j];
            }
        }
        __syncthreads();

        bfrag af[WTM], bfr[WTN];
        #pragma unroll
        for (int mt = 0; mt < WTM; ++mt)
            af[mt] = *(const bfrag*)&sA[(wm * WTM * 16 + mt * 16 + mrow) * LSTR + kgrp * 8];
        #pragma unroll
        for (int nt = 0; nt < WTN; ++nt)
            bfr[nt] = *(const bfrag*)&sB[(wn * WTN * 16 + nt * 16 + mrow) * LSTR + kgrp * 8];
        #pragma unroll
        for (int mt = 0; mt < WTM; ++mt)
            #pragma unroll
            for (int nt = 0; nt < WTN; ++nt)
                acc[mt][nt] = __builtin_amdgcn_mfma_f32_16x16x32_bf16(af[mt], bfr[nt], acc[mt][nt], 0, 0, 0);
        __syncthreads();
    }

    #pragma unroll
    for (int mt = 0; mt < WTM; ++mt) {
        #pragma unroll
        for (int nt = 0; nt < WTN; ++nt) {
            int grow0 = bm0 + wm * WTM * 16 + mt * 16 + kgrp * 4;
            int gcol  = bn0 + wn * WTN * 16 + nt * 16 + mrow;
            #pragma unroll
            for (int r = 0; r < 4; ++r) {
                float v = acc[mt][nt][r];
                size_t off = (size_t)(grow0 + r) * N + gcol;
                if (EPI == 0) {
                    Cb[off] = f2bf(v * scale);
                } else if (EPI == 1) {
                    Cb[off] = f2bf(1.0f / (1.0f + __expf(-v)));
                } else {
                    Cf[off] = v + bias[gcol] + bf2f(R[off]);
                }
            }
        }
    }
}

// LayerNorm over rows of 576 fp32. One wave per row, 4 rows per block.
template<bool OUT_BF>
__global__ __launch_bounds__(256) void ln_rows(
    const float* __restrict__ x, const float* __restrict__ g,
    const float* __restrict__ bb, void* __restrict__ outp)
{
    const int row  = blockIdx.x * 4 + (threadIdx.x >> 6);
    const int lane = threadIdx.x & 63;
    const float* xr = x + (size_t)row * 576;
    float vals[9];
    float s = 0.f, ss = 0.f;
    #pragma unroll
    for (int i = 0; i < 9; ++i) {
        float v = xr[lane + i * 64];
        vals[i] = v; s += v; ss += v * v;
    }
    #pragma unroll
    for (int off = 32; off > 0; off >>= 1) {
        s  += __shfl_xor(s, off, 64);
        ss += __shfl_xor(ss, off, 64);
    }
    float mean = s * (1.0f / 576.0f);
    float var  = ss * (1.0f / 576.0f) - mean * mean;
    float rstd = rsqrtf(var + 1e-5f);
    #pragma unroll
    for (int i = 0; i < 9; ++i) {
        int c = lane + i * 64;
        float o = (vals[i] - mean) * rstd * g[c] + bb[c];
        if (OUT_BF) ((unsigned short*)outp)[(size_t)row * 576 + c] = f2bf(o);
        else        ((float*)outp)[(size_t)row * 576 + c] = o;
    }
}

__global__ __launch_bounds__(256) void cvt4(const float* __restrict__ src,
                                            unsigned short* __restrict__ dst)
{
    int i = (blockIdx.x * 256 + threadIdx.x) * 4;
    float4 f = *(const float4*)(src + i);
    ushort4 o;
    o.x = f2bf(f.x); o.y = f2bf(f.y); o.z = f2bf(f.z); o.w = f2bf(f.w);
    *(ushort4*)(dst + i) = o;
}

extern "C" void kernel_launch(void* const* d_in, const int* in_sizes, int n_in,
                              void* d_out, int out_size, void* d_ws, size_t ws_size,
                              hipStream_t stream)
{
    const float* x  = (const float*)d_in[0];
    const float* y  = (const float*)d_in[1];
    const float* Wq = (const float*)d_in[2];
    const float* Wk = (const float*)d_in[3];
    const float* Wv = (const float*)d_in[4];
    const float* Wp = (const float*)d_in[5];
    const float* bp = (const float*)d_in[6];
    const float* gx = (const float*)d_in[7];
    const float* bx = (const float*)d_in[8];
    const float* gy = (const float*)d_in[9];
    const float* by = (const float*)d_in[10];
    const float* gz = (const float*)d_in[11];
    const float* bz = (const float*)d_in[12];

    constexpr size_t WB = 576 * 576 * 2;           // one bf16 weight matrix
    constexpr size_t XB = 16384ull * 576 * 2;      // one bf16 activation [16384,576]

    char* w = (char*)d_ws;
    unsigned short* wq = (unsigned short*)(w);
    unsigned short* wk = (unsigned short*)(w + WB);
    unsigned short* wv = (unsigned short*)(w + 2 * WB);
    unsigned short* wp = (unsigned short*)(w + 3 * WB);
    unsigned short* xn = (unsigned short*)(w + 4 * WB);
    unsigned short* yn = (unsigned short*)(w + 4 * WB + XB);
    unsigned short* q  = (unsigned short*)(w + 4 * WB + 2 * XB);
    unsigned short* k  = (unsigned short*)(w + 4 * WB + 3 * XB);
    unsigned short* v  = (unsigned short*)(w + 4 * WB + 4 * XB);
    unsigned short* S  = (unsigned short*)(w + 4 * WB + 5 * XB);  // 2048x2048 bf16, reused per batch
    unsigned short* attno = yn;       // yn dead after q projection
    float* T = (float*)q;             // q,k dead after attention; fp32 T = exactly q+k bytes

    cvt4<<<324, 256, 0, stream>>>(Wq, wq);
    cvt4<<<324, 256, 0, stream>>>(Wk, wk);
    cvt4<<<324, 256, 0, stream>>>(Wv, wv);
    cvt4<<<324, 256, 0, stream>>>(Wp, wp);

    ln_rows<true><<<4096, 256, 0, stream>>>(x, gx, bx, xn);
    ln_rows<true><<<4096, 256, 0, stream>>>(y, gy, by, yn);

    const float SCALE = 0.041666666666666664f;  // 576^-0.5 = 1/24, folded into q
    gemm_k<128, 64, 0, true><<<dim3(128, 9), 256, 0, stream>>>(yn, wq, q, nullptr, nullptr, nullptr, 16384, 576, 576, SCALE);
    gemm_k<128, 64, 0, true><<<dim3(128, 9), 256, 0, stream>>>(xn, wk, k, nullptr, nullptr, nullptr, 16384, 576, 576, 1.0f);
    gemm_k<128, 64, 0, true><<<dim3(128, 9), 256, 0, stream>>>(xn, wv, v, nullptr, nullptr, nullptr, 16384, 576, 576, 1.0f);

    for (int b = 0; b < 8; ++b) {
        const unsigned short* qb = q + (size_t)b * 2048 * 576;
        const unsigned short* kb = k + (size_t)b * 2048 * 576;
        const unsigned short* vb = v + (size_t)b * 2048 * 576;
        unsigned short* ob = attno + (size_t)b * 2048 * 576;
        // S_b = sigmoid(q_b * k_b^T)   [2048 x 2048]
        gemm_k<128, 128, 1, true><<<dim3(16, 16), 256, 0, stream>>>(qb, kb, S, nullptr, nullptr, nullptr, 2048, 2048, 576, 1.0f);
        // O_b = S_b * v_b              [2048 x 576]
        gemm_k<128, 64, 0, false><<<dim3(16, 9), 256, 0, stream>>>(S, vb, ob, nullptr, nullptr, nullptr, 2048, 576, 2048, 1.0f);
    }

    // T = attno * Wp^T + bp + xn   (fp32)
    gemm_k<128, 64, 2, true><<<dim3(128, 9), 256, 0, stream>>>(attno, wp, nullptr, T, xn, bp, 16384, 576, 576, 1.0f);
    // out = LN(T) (fp32)
    ln_rows<false><<<4096, 256, 0, stream>>>(T, gz, bz, d_out);
}

// Round 2
// 495.689 us; speedup vs baseline: 1.6259x; 1.6259x over previous
//
#include <hip/hip_runtime.h>

typedef __bf16 bfrag __attribute__((ext_vector_type(8)));
typedef float f32x4 __attribute__((ext_vector_type(4)));

__device__ __forceinline__ unsigned short f2bf(float f) {
    unsigned int u = __float_as_uint(f);
    unsigned int r = (u + 0x7fffu + ((u >> 16) & 1u)) >> 16;
    return (unsigned short)r;
}
__device__ __forceinline__ float bf2f(unsigned short h) {
    return __uint_as_float(((unsigned int)h) << 16);
}

// C = A[M,K] * B^T where B is [N,K] (NT). Batched over blockIdx.z via element strides.
// EPI: 0 = store bf16 (v*scale)
//      1 = sigmoid -> bf16
//      2 = +bias[col] + residual bf16 -> f32
//      3 = V-transpose pack: Vt[token>>11][col][token&2047] <- bf16, 8B stores
template<int BM, int BN, int EPI>
__global__ __launch_bounds__(256) void gemm_nt(
    const unsigned short* __restrict__ A, const unsigned short* __restrict__ B,
    unsigned short* __restrict__ Cb, float* __restrict__ Cf,
    const unsigned short* __restrict__ R, const float* __restrict__ bias,
    int M, int N, int K, float scale,
    size_t sAz, size_t sBz, size_t sCz)
{
    constexpr int BK = 32;
    constexpr int LSTR = BK + 8;          // +8 bf16 pad: 16B-aligned, breaks pow2 bank stride
    constexpr int WTM = BM / 32;          // 16x16 m-tiles per wave (2x2 wave grid)
    constexpr int WTN = BN / 32;
    __shared__ unsigned short sA[BM * LSTR];
    __shared__ unsigned short sB[BN * LSTR];

    A += blockIdx.z * sAz;
    B += blockIdx.z * sBz;

    const int tid  = threadIdx.x;
    const int wave = tid >> 6;
    const int lane = tid & 63;
    const int wm = wave >> 1;
    const int wn = wave & 1;
    const int bm0 = blockIdx.x * BM;
    const int bn0 = blockIdx.y * BN;
    const int mrow = lane & 15;
    const int kgrp = lane >> 4;

    f32x4 acc[WTM][WTN] = {};

    for (int k0 = 0; k0 < K; k0 += BK) {
        {   // stage A tile [BM x 32], 16B vector loads
            constexpr int PER = (BM * BK / 8) / 256;
            #pragma unroll
            for (int i = 0; i < PER; ++i) {
                int idx = tid + i * 256;
                int r = idx >> 2, c = idx & 3;
                uint4 d = *(const uint4*)(A + (size_t)(bm0 + r) * K + k0 + c * 8);
                *(uint4*)&sA[r * LSTR + c * 8] = d;
            }
        }
        {   // stage B tile [BN x 32]
            constexpr int PER = (BN * BK / 8) / 256;
            #pragma unroll
            for (int i = 0; i < PER; ++i) {
                int idx = tid + i * 256;
                int r = idx >> 2, c = idx & 3;
                uint4 d = *(const uint4*)(B + (size_t)(bn0 + r) * K + k0 + c * 8);
                *(uint4*)&sB[r * LSTR + c * 8] = d;
            }
        }
        __syncthreads();

        bfrag af[WTM], bfr[WTN];
        #pragma unroll
        for (int mt = 0; mt < WTM; ++mt)
            af[mt] = *(const bfrag*)&sA[(wm * WTM * 16 + mt * 16 + mrow) * LSTR + kgrp * 8];
        #pragma unroll
        for (int nt = 0; nt < WTN; ++nt)
            bfr[nt] = *(const bfrag*)&sB[(wn * WTN * 16 + nt * 16 + mrow) * LSTR + kgrp * 8];
        #pragma unroll
        for (int mt = 0; mt < WTM; ++mt)
            #pragma unroll
            for (int nt = 0; nt < WTN; ++nt)
                acc[mt][nt] = __builtin_amdgcn_mfma_f32_16x16x32_bf16(af[mt], bfr[nt], acc[mt][nt], 0, 0, 0);
        __syncthreads();
    }

    #pragma unroll
    for (int mt = 0; mt < WTM; ++mt) {
        #pragma unroll
        for (int nt = 0; nt < WTN; ++nt) {
            int grow0 = bm0 + wm * WTM * 16 + mt * 16 + kgrp * 4;
            int gcol  = bn0 + wn * WTN * 16 + nt * 16 + mrow;
            if (EPI == 3) {
                // rows grow0..grow0+3 are consecutive tokens within one batch
                // (tiles are 16-aligned, batches 2048-aligned) -> one 8B store
                ushort4 o;
                o.x = f2bf(acc[mt][nt][0]);
                o.y = f2bf(acc[mt][nt][1]);
                o.z = f2bf(acc[mt][nt][2]);
                o.w = f2bf(acc[mt][nt][3]);
                size_t dst = (((size_t)(grow0 >> 11) * 576 + gcol) << 11) + (grow0 & 2047);
                *(ushort4*)(Cb + dst) = o;
            } else {
                #pragma unroll
                for (int r = 0; r < 4; ++r) {
                    float v = acc[mt][nt][r];
                    size_t off = blockIdx.z * sCz + (size_t)(grow0 + r) * N + gcol;
                    if (EPI == 0) {
                        Cb[off] = f2bf(v * scale);
                    } else if (EPI == 1) {
                        Cb[off] = f2bf(1.0f / (1.0f + __expf(-v)));
                    } else {
                        Cf[off] = v + bias[gcol] + bf2f(R[off]);
                    }
                }
            }
        }
    }
}

// LayerNorm over rows of 576 fp32. One wave per row, 4 rows per block.
template<bool OUT_BF>
__global__ __launch_bounds__(256) void ln_rows(
    const float* __restrict__ x, const float* __restrict__ g,
    const float* __restrict__ bb, void* __restrict__ outp)
{
    const int row  = blockIdx.x * 4 + (threadIdx.x >> 6);
    const int lane = threadIdx.x & 63;
    const float* xr = x + (size_t)row * 576;
    float vals[9];
    float s = 0.f, ss = 0.f;
    #pragma unroll
    for (int i = 0; i < 9; ++i) {
        float v = xr[lane + i * 64];
        vals[i] = v; s += v; ss += v * v;
    }
    #pragma unroll
    for (int off = 32; off > 0; off >>= 1) {
        s  += __shfl_xor(s, off, 64);
        ss += __shfl_xor(ss, off, 64);
    }
    float mean = s * (1.0f / 576.0f);
    float var  = ss * (1.0f / 576.0f) - mean * mean;
    float rstd = rsqrtf(var + 1e-5f);
    #pragma unroll
    for (int i = 0; i < 9; ++i) {
        int c = lane + i * 64;
        float o = (vals[i] - mean) * rstd * g[c] + bb[c];
        if (OUT_BF) ((unsigned short*)outp)[(size_t)row * 576 + c] = f2bf(o);
        else        ((float*)outp)[(size_t)row * 576 + c] = o;
    }
}

__global__ __launch_bounds__(256) void cvt4(const float* __restrict__ src,
                                            unsigned short* __restrict__ dst)
{
    int i = (blockIdx.x * 256 + threadIdx.x) * 4;
    float4 f = *(const float4*)(src + i);
    ushort4 o;
    o.x = f2bf(f.x); o.y = f2bf(f.y); o.z = f2bf(f.z); o.w = f2bf(f.w);
    *(ushort4*)(dst + i) = o;
}

extern "C" void kernel_launch(void* const* d_in, const int* in_sizes, int n_in,
                              void* d_out, int out_size, void* d_ws, size_t ws_size,
                              hipStream_t stream)
{
    const float* x  = (const float*)d_in[0];
    const float* y  = (const float*)d_in[1];
    const float* Wq = (const float*)d_in[2];
    const float* Wk = (const float*)d_in[3];
    const float* Wv = (const float*)d_in[4];
    const float* Wp = (const float*)d_in[5];
    const float* bp = (const float*)d_in[6];
    const float* gx = (const float*)d_in[7];
    const float* bx = (const float*)d_in[8];
    const float* gy = (const float*)d_in[9];
    const float* by = (const float*)d_in[10];
    const float* gz = (const float*)d_in[11];
    const float* bz = (const float*)d_in[12];

    constexpr size_t WB = 576 * 576 * 2;           // one bf16 weight matrix
    constexpr size_t XB = 16384ull * 576 * 2;      // one bf16 activation [16384,576]
    constexpr size_t TOK = (size_t)2048 * 576;     // elements per batch of activation

    char* w = (char*)d_ws;
    unsigned short* wq = (unsigned short*)(w);
    unsigned short* wk = (unsigned short*)(w + WB);
    unsigned short* wv = (unsigned short*)(w + 2 * WB);
    unsigned short* wp = (unsigned short*)(w + 3 * WB);
    unsigned short* xn = (unsigned short*)(w + 4 * WB);
    unsigned short* yn = (unsigned short*)(w + 4 * WB + XB);
    unsigned short* q  = (unsigned short*)(w + 4 * WB + 2 * XB);
    unsigned short* k  = (unsigned short*)(w + 4 * WB + 3 * XB);
    unsigned short* vt = (unsigned short*)(w + 4 * WB + 4 * XB);  // [8][576][2048] bf16
    unsigned short* S  = (unsigned short*)(w + 4 * WB + 5 * XB);  // 2 x 2048x2048 bf16
    unsigned short* attno = yn;       // yn dead after q projection
    float* T = (float*)q;             // q,k dead after attention; fp32 T = exactly q+k bytes

    cvt4<<<324, 256, 0, stream>>>(Wq, wq);
    cvt4<<<324, 256, 0, stream>>>(Wk, wk);
    cvt4<<<324, 256, 0, stream>>>(Wv, wv);
    cvt4<<<324, 256, 0, stream>>>(Wp, wp);

    ln_rows<true><<<4096, 256, 0, stream>>>(x, gx, bx, xn);
    ln_rows<true><<<4096, 256, 0, stream>>>(y, gy, by, yn);

    const float SCALE = 0.041666666666666664f;  // 576^-0.5 = 1/24, folded into q
    gemm_nt<128, 64, 0><<<dim3(128, 9, 1), 256, 0, stream>>>(
        yn, wq, q, nullptr, nullptr, nullptr, 16384, 576, 576, SCALE, 0, 0, 0);
    gemm_nt<128, 64, 0><<<dim3(128, 9, 1), 256, 0, stream>>>(
        xn, wk, k, nullptr, nullptr, nullptr, 16384, 576, 576, 1.0f, 0, 0, 0);
    gemm_nt<128, 64, 3><<<dim3(128, 9, 1), 256, 0, stream>>>(
        xn, wv, vt, nullptr, nullptr, nullptr, 16384, 576, 576, 1.0f, 0, 0, 0);

    // attention in pairs of batches: z in {0,1} selects batch within pair
    for (int p = 0; p < 4; ++p) {
        const unsigned short* qb  = q  + (size_t)p * 2 * TOK;
        const unsigned short* kb  = k  + (size_t)p * 2 * TOK;
        const unsigned short* vtb = vt + (size_t)p * 2 * TOK;
        unsigned short* ob = attno + (size_t)p * 2 * TOK;
        // S_z = sigmoid(q_z * k_z^T)   [2048 x 2048] x2
        gemm_nt<128, 128, 1><<<dim3(16, 16, 2), 256, 0, stream>>>(
            qb, kb, S, nullptr, nullptr, nullptr, 2048, 2048, 576, 1.0f,
            TOK, TOK, (size_t)2048 * 2048);
        // O_z = S_z * v_z  via NT against Vt  [2048 x 576] x2
        gemm_nt<64, 64, 0><<<dim3(32, 9, 2), 256, 0, stream>>>(
            S, vtb, ob, nullptr, nullptr, nullptr, 2048, 576, 2048, 1.0f,
            (size_t)2048 * 2048, TOK, TOK);
    }

    // T = attno * Wp^T + bp + xn   (fp32)
    gemm_nt<128, 64, 2><<<dim3(128, 9, 1), 256, 0, stream>>>(
        attno, wp, nullptr, T, xn, bp, 16384, 576, 576, 1.0f, 0, 0, 0);
    // out = LN(T) (fp32)
    ln_rows<false><<<4096, 256, 0, stream>>>(T, gz, bz, d_out);
}

// Round 3
// 403.485 us; speedup vs baseline: 1.9974x; 1.2285x over previous
//
#include <hip/hip_runtime.h>

typedef __bf16 bfrag __attribute__((ext_vector_type(8)));
typedef float f32x4 __attribute__((ext_vector_type(4)));

__device__ __forceinline__ unsigned short f2bf(float f) {
    unsigned int u = __float_as_uint(f);
    unsigned int r = (u + 0x7fffu + ((u >> 16) & 1u)) >> 16;
    return (unsigned short)r;
}
__device__ __forceinline__ float bf2f(unsigned short h) {
    return __uint_as_float(((unsigned int)h) << 16);
}

__device__ __forceinline__ void gll16(const unsigned short* g, unsigned short* l) {
    __builtin_amdgcn_global_load_lds(
        (const __attribute__((address_space(1))) unsigned int*)g,
        (__attribute__((address_space(3))) unsigned int*)l, 16, 0, 0);
}

// C = A[M,K] * B^T, B is [N,K] (NT). Batched over blockIdx.z via element strides.
// Waves arranged WR x WC (WR*WC=4). LDS tiles unpadded (global_load_lds lane order);
// frag ds_read_b128 of 16 consecutive rows x 64B = contiguous 1KB -> conflict-free.
// EPI: 0 = store bf16 (v*scale)
//      1 = sigmoid -> bf16
//      2 = +bias[col] + residual bf16 -> f32
//      3 = V-transpose pack: Vt[token>>11][col][token&2047] <- bf16, 8B stores
template<int BM, int BN, int WR, int WC, int EPI>
__global__ __launch_bounds__(256) void gemm_nt(
    const unsigned short* __restrict__ A, const unsigned short* __restrict__ B,
    unsigned short* __restrict__ Cb, float* __restrict__ Cf,
    const unsigned short* __restrict__ R, const float* __restrict__ bias,
    int M, int N, int K, float scale,
    size_t sAz, size_t sBz, size_t sCz)
{
    constexpr int BK = 32;
    constexpr int WTM = BM / (WR * 16);
    constexpr int WTN = BN / (WC * 16);
    __shared__ unsigned short sA[BM * BK];
    __shared__ unsigned short sB[BN * BK];

    A += blockIdx.z * sAz;
    B += blockIdx.z * sBz;

    const int tid  = threadIdx.x;
    const int wave = tid >> 6;
    const int lane = tid & 63;
    const int wm = wave / WC;
    const int wn = wave % WC;
    const int bm0 = blockIdx.x * BM;
    const int bn0 = blockIdx.y * BN;
    const int mrow = lane & 15;
    const int kgrp = lane >> 4;

    f32x4 acc[WTM][WTN] = {};

    for (int k0 = 0; k0 < K; k0 += BK) {
        // stage A tile [BM x 32] bf16, direct global->LDS 16B DMA
        #pragma unroll
        for (int i = 0; i < BM / 64; ++i) {
            int idx = tid + i * 256;
            int r = idx >> 2, c = idx & 3;
            gll16(A + (size_t)(bm0 + r) * K + k0 + c * 8, &sA[idx * 8]);
        }
        #pragma unroll
        for (int i = 0; i < BN / 64; ++i) {
            int idx = tid + i * 256;
            int r = idx >> 2, c = idx & 3;
            gll16(B + (size_t)(bn0 + r) * K + k0 + c * 8, &sB[idx * 8]);
        }
        __syncthreads();

        bfrag af[WTM], bfr[WTN];
        #pragma unroll
        for (int mt = 0; mt < WTM; ++mt)
            af[mt] = *(const bfrag*)&sA[(wm * WTM * 16 + mt * 16 + mrow) * BK + kgrp * 8];
        #pragma unroll
        for (int nt = 0; nt < WTN; ++nt)
            bfr[nt] = *(const bfrag*)&sB[(wn * WTN * 16 + nt * 16 + mrow) * BK + kgrp * 8];
        #pragma unroll
        for (int mt = 0; mt < WTM; ++mt)
            #pragma unroll
            for (int nt = 0; nt < WTN; ++nt)
                acc[mt][nt] = __builtin_amdgcn_mfma_f32_16x16x32_bf16(af[mt], bfr[nt], acc[mt][nt], 0, 0, 0);
        __syncthreads();
    }

    #pragma unroll
    for (int mt = 0; mt < WTM; ++mt) {
        #pragma unroll
        for (int nt = 0; nt < WTN; ++nt) {
            int grow0 = bm0 + wm * WTM * 16 + mt * 16 + kgrp * 4;
            int gcol  = bn0 + wn * WTN * 16 + nt * 16 + mrow;
            if (EPI == 3) {
                // rows grow0..grow0+3 = consecutive tokens in one batch -> one 8B store
                ushort4 o;
                o.x = f2bf(acc[mt][nt][0]);
                o.y = f2bf(acc[mt][nt][1]);
                o.z = f2bf(acc[mt][nt][2]);
                o.w = f2bf(acc[mt][nt][3]);
                size_t dst = (((size_t)(grow0 >> 11) * 576 + gcol) << 11) + (grow0 & 2047);
                *(ushort4*)(Cb + dst) = o;
            } else {
                #pragma unroll
                for (int r = 0; r < 4; ++r) {
                    float v = acc[mt][nt][r];
                    size_t off = blockIdx.z * sCz + (size_t)(grow0 + r) * N + gcol;
                    if (EPI == 0) {
                        Cb[off] = f2bf(v * scale);
                    } else if (EPI == 1) {
                        Cb[off] = f2bf(1.0f / (1.0f + __expf(-v)));
                    } else {
                        Cf[off] = v + bias[gcol] + bf2f(R[off]);
                    }
                }
            }
        }
    }
}

// LayerNorm over rows of 576 fp32. One wave per row, 4 rows per block.
template<bool OUT_BF>
__global__ __launch_bounds__(256) void ln_rows(
    const float* __restrict__ x, const float* __restrict__ g,
    const float* __restrict__ bb, void* __restrict__ outp)
{
    const int row  = blockIdx.x * 4 + (threadIdx.x >> 6);
    const int lane = threadIdx.x & 63;
    const float* xr = x + (size_t)row * 576;
    float vals[9];
    float s = 0.f, ss = 0.f;
    #pragma unroll
    for (int i = 0; i < 9; ++i) {
        float v = xr[lane + i * 64];
        vals[i] = v; s += v; ss += v * v;
    }
    #pragma unroll
    for (int off = 32; off > 0; off >>= 1) {
        s  += __shfl_xor(s, off, 64);
        ss += __shfl_xor(ss, off, 64);
    }
    float mean = s * (1.0f / 576.0f);
    float var  = ss * (1.0f / 576.0f) - mean * mean;
    float rstd = rsqrtf(var + 1e-5f);
    #pragma unroll
    for (int i = 0; i < 9; ++i) {
        int c = lane + i * 64;
        float o = (vals[i] - mean) * rstd * g[c] + bb[c];
        if (OUT_BF) ((unsigned short*)outp)[(size_t)row * 576 + c] = f2bf(o);
        else        ((float*)outp)[(size_t)row * 576 + c] = o;
    }
}

// 4 weight matrices fp32 -> bf16, blockIdx.y selects which
__global__ __launch_bounds__(256) void cvt4w(
    const float* __restrict__ s0, const float* __restrict__ s1,
    const float* __restrict__ s2, const float* __restrict__ s3,
    unsigned short* __restrict__ dst)
{
    const float* srcs[4] = {s0, s1, s2, s3};
    const float* src = srcs[blockIdx.y];
    unsigned short* d = dst + (size_t)blockIdx.y * 576 * 576;
    int i = (blockIdx.x * 256 + threadIdx.x) * 4;
    float4 f = *(const float4*)(src + i);
    ushort4 o;
    o.x = f2bf(f.x); o.y = f2bf(f.y); o.z = f2bf(f.z); o.w = f2bf(f.w);
    *(ushort4*)(d + i) = o;
}

extern "C" void kernel_launch(void* const* d_in, const int* in_sizes, int n_in,
                              void* d_out, int out_size, void* d_ws, size_t ws_size,
                              hipStream_t stream)
{
    const float* x  = (const float*)d_in[0];
    const float* y  = (const float*)d_in[1];
    const float* Wq = (const float*)d_in[2];
    const float* Wk = (const float*)d_in[3];
    const float* Wv = (const float*)d_in[4];
    const float* Wp = (const float*)d_in[5];
    const float* bp = (const float*)d_in[6];
    const float* gx = (const float*)d_in[7];
    const float* bx = (const float*)d_in[8];
    const float* gy = (const float*)d_in[9];
    const float* by = (const float*)d_in[10];
    const float* gz = (const float*)d_in[11];
    const float* bz = (const float*)d_in[12];

    constexpr size_t WB = 576 * 576 * 2;           // one bf16 weight matrix (bytes)
    constexpr size_t XB = 16384ull * 576 * 2;      // one bf16 activation [16384,576] (bytes)
    constexpr size_t TOK = (size_t)2048 * 576;     // elements per batch of activation
    constexpr size_t SB  = (size_t)2048 * 2048;    // elements per batch of S

    char* w = (char*)d_ws;
    unsigned short* wq = (unsigned short*)(w);
    unsigned short* wk = (unsigned short*)(w + WB);
    unsigned short* wv = (unsigned short*)(w + 2 * WB);
    unsigned short* wp = (unsigned short*)(w + 3 * WB);
    unsigned short* xn = (unsigned short*)(w + 4 * WB);
    unsigned short* yn = (unsigned short*)(w + 4 * WB + XB);
    unsigned short* q  = (unsigned short*)(w + 4 * WB + 2 * XB);
    unsigned short* k  = (unsigned short*)(w + 4 * WB + 3 * XB);
    unsigned short* vt = (unsigned short*)(w + 4 * WB + 4 * XB);  // [8][576][2048] bf16
    unsigned short* S  = (unsigned short*)(w + 4 * WB + 5 * XB);  // [8][2048][2048] bf16, 67 MB
    unsigned short* attno = yn;       // yn dead after q projection
    float* T = (float*)q;             // q,k dead after attention; fp32 T = exactly q+k bytes

    cvt4w<<<dim3(324, 4), 256, 0, stream>>>(Wq, Wk, Wv, Wp, wq);

    ln_rows<true><<<4096, 256, 0, stream>>>(x, gx, bx, xn);
    ln_rows<true><<<4096, 256, 0, stream>>>(y, gy, by, yn);

    const float SCALE = 0.041666666666666664f;  // 576^-0.5 = 1/24, folded into q
    gemm_nt<256, 64, 4, 1, 0><<<dim3(64, 9, 1), 256, 0, stream>>>(
        yn, wq, q, nullptr, nullptr, nullptr, 16384, 576, 576, SCALE, 0, 0, 0);
    gemm_nt<256, 64, 4, 1, 0><<<dim3(64, 9, 1), 256, 0, stream>>>(
        xn, wk, k, nullptr, nullptr, nullptr, 16384, 576, 576, 1.0f, 0, 0, 0);
    gemm_nt<256, 64, 4, 1, 3><<<dim3(64, 9, 1), 256, 0, stream>>>(
        xn, wv, vt, nullptr, nullptr, nullptr, 16384, 576, 576, 1.0f, 0, 0, 0);

    // S_b = sigmoid(q_b * k_b^T)  [2048 x 2048] x 8 batches, one launch
    gemm_nt<128, 128, 2, 2, 1><<<dim3(16, 16, 8), 256, 0, stream>>>(
        q, k, S, nullptr, nullptr, nullptr, 2048, 2048, 576, 1.0f, TOK, TOK, SB);
    // O_b = S_b * v_b  via NT against Vt  [2048 x 576] x 8 batches, one launch
    gemm_nt<256, 64, 4, 1, 0><<<dim3(8, 9, 8), 256, 0, stream>>>(
        S, vt, attno, nullptr, nullptr, nullptr, 2048, 576, 2048, 1.0f, SB, TOK, TOK);

    // T = attno * Wp^T + bp + xn   (fp32)
    gemm_nt<256, 64, 4, 1, 2><<<dim3(64, 9, 1), 256, 0, stream>>>(
        attno, wp, nullptr, T, xn, bp, 16384, 576, 576, 1.0f, 0, 0, 0);
    // out = LN(T) (fp32)
    ln_rows<false><<<4096, 256, 0, stream>>>(T, gz, bz, d_out);
}